// Round 9
// baseline (37423.178 us; speedup 1.0000x reference)
//
#include <hip/hip_runtime.h>

#define SEQ 65536
#define IN_DIM 64
#define H 128
#define G4 512

typedef _Float16 half_t;
typedef half_t half2_t __attribute__((ext_vector_type(2)));
typedef half_t half8_t __attribute__((ext_vector_type(8)));
typedef int    i4     __attribute__((ext_vector_type(4)));
typedef unsigned int uint_t;

__device__ __forceinline__ float fast_rcp(float x) { return __builtin_amdgcn_rcpf(x); }

// no clamp: exp overflow -> inf -> rcp -> 0, the correct sigmoid limit
__device__ __forceinline__ float sigmoid_f(float x) {
    return fast_rcp(1.f + __expf(-x));
}

#if __has_builtin(__builtin_amdgcn_fdot2)
__device__ __forceinline__ float dot2i(int w, int h, float acc) {
    return __builtin_amdgcn_fdot2(__builtin_bit_cast(half2_t, w),
                                  __builtin_bit_cast(half2_t, h), acc, false);
}
#else
__device__ __forceinline__ float dot2i(int w, int h, float acc) {
    half2_t a = __builtin_bit_cast(half2_t, w);
    half2_t b = __builtin_bit_cast(half2_t, h);
    return acc + (float)a[0] * (float)b[0] + (float)a[1] * (float)b[1];
}
#endif

// two f32 -> one VGPR of packed 2xf16 (single v_cvt_pkrtz_f16_f32)
__device__ __forceinline__ int pk(float a, float b) {
    return __builtin_bit_cast(int, __builtin_amdgcn_cvt_pkrtz(a, b));
}

// 8 fp32 (two float4 loads) -> int4 of packed half2s.
// NO v8f16 anywhere: int4 elements are exact VGPRs, extracts are subregs.
__device__ __forceinline__ i4 cvt8i(const float* p) {
    float4 a = *(const float4*)p;
    float4 b = *(const float4*)(p + 4);
    i4 r;
    r[0] = pk(a.x, a.y); r[1] = pk(a.z, a.w);
    r[2] = pk(b.x, b.y); r[3] = pk(b.z, b.w);
    return r;
}

// quad-lane exchanges via DPP (VALU pipe). Control must be a constant -> template.
template <int CTRL>
__device__ __forceinline__ float qperm(float x) {
    return __int_as_float(
        __builtin_amdgcn_mov_dpp(__float_as_int(x), CTRL, 0xF, 0xF, true));
}
#define qx1(x)  qperm<0xB1>(x) /* quad_perm [1,0,3,2] lane^1 */
#define qx2(x)  qperm<0x4E>(x) /* quad_perm [2,3,0,1] lane^2 */

// ---------------------------------------------------------------------------
// Phase A: xg[s][j*4+g] = dot(x[s], W_ih[g*128+j]) + b_ih + b_hh
// -> quad j reads ONE broadcast float4 per step (i,f,g,o gate biases).
// ---------------------------------------------------------------------------
__global__ __launch_bounds__(256) void xg_gemm(
    const float* __restrict__ x, const float* __restrict__ Wih,
    const float* __restrict__ bih, const float* __restrict__ bhh,
    float* __restrict__ xg)
{
    long long gid = (long long)blockIdx.x * 256 + threadIdx.x;
    int s = (int)(gid >> 9);
    int rr = (int)(gid & 511);
    int j = rr >> 2, g = rr & 3;
    int row = g * H + j;
    const float* xr = x + (long long)s * IN_DIM;
    const float* wr = Wih + (long long)row * IN_DIM;
    float a0 = 0.f, a1 = 0.f, a2 = 0.f, a3 = 0.f;
#pragma unroll
    for (int k = 0; k < IN_DIM; k += 4) {
        float4 iv = *(const float4*)(xr + k);
        float4 wv = *(const float4*)(wr + k);
        a0 += wv.x * iv.x; a1 += wv.y * iv.y;
        a2 += wv.z * iv.z; a3 += wv.w * iv.w;
    }
    xg[gid] = (a0 + a1) + (a2 + a3) + bih[row] + bhh[row];
}

// ---------------------------------------------------------------------------
// Phase B: persistent 512-thread (8-wave, 2/SIMD) scan.
// Geometry identical to R6-R8. ONE structural change: all f16 data lives in
// int/int4 (packed half2 per VGPR). R2-R8 evidence: VALUBusy ~80% of CU at
// ~500 VALU instrs/thread/step = 5x the intended stream -> v8f16
// extract/repack churn (pick2 = shufflevector on v8f16, tracked at 32-bit
// granularity by the backend, lowered to cvt/pack chains). int4 elements are
// exact VGPRs; bit_cast to half2 for fdot2 is a register-level no-op.
// ---------------------------------------------------------------------------
__attribute__((amdgpu_waves_per_eu(2, 2)))
__global__ __launch_bounds__(512) void lstm_scan(
    const float* __restrict__ Whh, const float* __restrict__ Wlin,
    const float* __restrict__ blin, const float* __restrict__ xg,
    float* __restrict__ out)
{
    __shared__ __align__(16) half_t shbuf[2][H]; // 512 B double-buffered h
    const int tid = threadIdx.x;
    const int ql = tid & 3;
    const int j  = tid >> 2;           // cell 0..127
    const int c0 = ql * 32;

    // ---- weights: 4 gate rows x 32 cols as 16 named int4 (64 VGPRs) ----
#define LOADW(P, ROW)                                                     \
    i4 P##0 = cvt8i(Whh + (size_t)(ROW) * H + c0 + 0),                    \
       P##1 = cvt8i(Whh + (size_t)(ROW) * H + c0 + 8),                    \
       P##2 = cvt8i(Whh + (size_t)(ROW) * H + c0 + 16),                   \
       P##3 = cvt8i(Whh + (size_t)(ROW) * H + c0 + 24);
    LOADW(wi, j)
    LOADW(wf, 128 + j)
    LOADW(wg, 256 + j)
    LOADW(wo, 384 + j)
#undef LOADW
    // PIN: opaque asm outputs -> unsinkable, un-remat-able
#define PIN(A, B, C, D) asm volatile("" : "+v"(A), "+v"(B), "+v"(C), "+v"(D))
    PIN(wi0, wi1, wi2, wi3);
    PIN(wf0, wf1, wf2, wf3);
    PIN(wg0, wg1, wg2, wg3);
    PIN(wo0, wo1, wo2, wo3);
#undef PIN

    const float* xgq = xg + (size_t)j * 4; // [s][j][gate] float4, quad-broadcast
    float c = 0.f;

    // xg ring: depth-2 prefetch (window ~2 steps > L3 miss latency)
    float4 xg_c = *(const float4*)(xgq + (size_t)0 * G4);
    float4 xg_n = *(const float4*)(xgq + (size_t)1 * G4);

    if (tid < H) shbuf[0][tid] = (half_t)0.f;
    __syncthreads();

#define DOT8(ACC, WV, HV)                                                 \
    ACC = dot2i(WV[0], HV[0], ACC);                                       \
    ACC = dot2i(WV[1], HV[1], ACC);                                       \
    ACC = dot2i(WV[2], HV[2], ACC);                                       \
    ACC = dot2i(WV[3], HV[3], ACC);
#define QRED(X) X += qx1(X); X += qx2(X);

#define STEP(RB, WB, T)                                                   \
    {                                                                     \
        const i4* hp = (const i4*)&shbuf[RB][c0];                         \
        i4 h0 = hp[0], h1 = hp[1], h2 = hp[2], h3 = hp[3];                \
        int tp = (T) + 2; if (tp > SEQ - 1) tp = SEQ - 1;                 \
        float4 xg_p = *(const float4*)(xgq + (size_t)tp * G4);            \
        float ai0 = 0.f, ai1 = 0.f, af0 = 0.f, af1 = 0.f;                 \
        float ag0 = 0.f, ag1 = 0.f, ao0 = 0.f, ao1 = 0.f;                 \
        DOT8(ai0, wi0, h0) DOT8(ai1, wi1, h1)                             \
        DOT8(ai0, wi2, h2) DOT8(ai1, wi3, h3)                             \
        DOT8(af0, wf0, h0) DOT8(af1, wf1, h1)                             \
        DOT8(af0, wf2, h2) DOT8(af1, wf3, h3)                             \
        DOT8(ag0, wg0, h0) DOT8(ag1, wg1, h1)                             \
        DOT8(ag0, wg2, h2) DOT8(ag1, wg3, h3)                             \
        DOT8(ao0, wo0, h0) DOT8(ao1, wo1, h1)                             \
        DOT8(ao0, wo2, h2) DOT8(ao1, wo3, h3)                             \
        float si = ai0 + ai1, sf = af0 + af1;                             \
        float sg = ag0 + ag1, so = ao0 + ao1;                             \
        QRED(si) QRED(sf) QRED(sg) QRED(so)                               \
        float gi = sigmoid_f(si + xg_c.x);                                \
        float gf = sigmoid_f(sf + xg_c.y);                                \
        float ug = sg + xg_c.z;                                           \
        float s2 = sigmoid_f(ug + ug);                                    \
        float gg = s2 + s2 - 1.f;        /* tanh = 2*sig(2x)-1 */         \
        float go = sigmoid_f(so + xg_c.w);                                \
        c = gf * c + gi * gg;                                             \
        float sc = sigmoid_f(c + c);                                      \
        float th = sc + sc - 1.f;                                         \
        float hh = go * th;                                               \
        if (ql == 0) shbuf[WB][j] = (half_t)hh;                           \
        asm volatile("s_waitcnt lgkmcnt(0)" ::: "memory");                \
        __builtin_amdgcn_s_barrier();                                     \
        __builtin_amdgcn_sched_barrier(0);                                \
        xg_c = xg_n; xg_n = xg_p;                                         \
    }

    for (int t = 0; t < SEQ; t += 2) {
        STEP(0, 1, t)
        STEP(1, 0, t + 1)
    }
#undef STEP
#undef QRED
#undef DOT8

    // h(SEQ) in shbuf[0]; one wave reduces the linear head.
    if (tid < 64) {
        float p = (float)shbuf[0][tid] * Wlin[tid] +
                  (float)shbuf[0][tid + 64] * Wlin[tid + 64];
#pragma unroll
        for (int off = 32; off > 0; off >>= 1) p += __shfl_down(p, off);
        if (tid == 0) out[0] = sigmoid_f(p + blin[0]);
    }
}

// ---------------------------------------------------------------------------
// Fallback (ws too small): int-packed variant of the round-2 kernel.
// ---------------------------------------------------------------------------
__global__ __launch_bounds__(512, 2) void lstm_scan_fb(
    const float* __restrict__ x, const float* __restrict__ Wih,
    const float* __restrict__ Whh, const float* __restrict__ bih,
    const float* __restrict__ bhh, const float* __restrict__ Wlin,
    const float* __restrict__ blin, float* __restrict__ out)
{
    __shared__ __align__(16) half_t sh_h[H];
    __shared__ __align__(16) float  sh_g[G4];
    const int row = threadIdx.x;
    const float* wrow = Whh + (long long)row * H;

    i4 w0 = cvt8i(wrow + 0),   w1 = cvt8i(wrow + 8);
    i4 w2 = cvt8i(wrow + 16),  w3 = cvt8i(wrow + 24);
    i4 w4 = cvt8i(wrow + 32),  w5 = cvt8i(wrow + 40);
    i4 w6 = cvt8i(wrow + 48),  w7 = cvt8i(wrow + 56);
    i4 w8 = cvt8i(wrow + 64),  w9 = cvt8i(wrow + 72);
    i4 w10 = cvt8i(wrow + 80), w11 = cvt8i(wrow + 88);
    i4 w12 = cvt8i(wrow + 96), w13 = cvt8i(wrow + 104);
    i4 w14 = cvt8i(wrow + 112), w15 = cvt8i(wrow + 120);

    const float bsum = bih[row] + bhh[row];
    float c = 0.f;
    if (row < H) sh_h[row] = (half_t)0.f;

    float xg_cur;
    {
        float a = bsum;
        const float* wir = Wih + (long long)row * IN_DIM;
#pragma unroll
        for (int k = 0; k < IN_DIM; k += 4) {
            float4 iv = *(const float4*)(x + k);
            float4 wv = *(const float4*)(wir + k);
            a += wv.x * iv.x + wv.y * iv.y + wv.z * iv.z + wv.w * iv.w;
        }
        xg_cur = a;
    }
    const bool is_g = (row >= 2 * H) && (row < 3 * H);
    __syncthreads();

    const i4* hch = (const i4*)sh_h;

    for (int t = 0; t < SEQ; ++t) {
        float xg_nxt = 0.f;
        if (t + 1 < SEQ) {
            const float* xr = x + (size_t)(t + 1) * IN_DIM;
            const float* wir = Wih + (long long)row * IN_DIM;
            float a = bsum;
#pragma unroll
            for (int k = 0; k < IN_DIM; k += 4) {
                float4 iv = *(const float4*)(xr + k);
                float4 wv = *(const float4*)(wir + k);
                a += wv.x * iv.x + wv.y * iv.y + wv.z * iv.z + wv.w * iv.w;
            }
            xg_nxt = a;
        }
        float a0 = 0.f, a1 = 0.f, a2 = 0.f, a3 = 0.f;
#define DOTC(WV, CI)                                                     \
        {   i4 hv = hch[CI];                                             \
            a0 = dot2i(WV[0], hv[0], a0);                                \
            a1 = dot2i(WV[1], hv[1], a1);                                \
            a2 = dot2i(WV[2], hv[2], a2);                                \
            a3 = dot2i(WV[3], hv[3], a3); }
        DOTC(w0, 0)  DOTC(w1, 1)  DOTC(w2, 2)   DOTC(w3, 3)
        DOTC(w4, 4)  DOTC(w5, 5)  DOTC(w6, 6)   DOTC(w7, 7)
        DOTC(w8, 8)  DOTC(w9, 9)  DOTC(w10, 10) DOTC(w11, 11)
        DOTC(w12, 12) DOTC(w13, 13) DOTC(w14, 14) DOTC(w15, 15)
#undef DOTC
        float pre = xg_cur + ((a0 + a1) + (a2 + a3));
        float gv;
        if (is_g) {
            float s = sigmoid_f(pre + pre);
            gv = s + s - 1.f;
        } else {
            gv = sigmoid_f(pre);
        }
        sh_g[row] = gv;
        __syncthreads();
        if (row >= 3 * H) {
            int jj = row - 3 * H;
            float ig = sh_g[jj];
            float fg = sh_g[H + jj];
            float gg = sh_g[2 * H + jj];
            c = fg * c + ig * gg;
            float s = sigmoid_f(c + c);
            sh_h[jj] = (half_t)(gv * (s + s - 1.f));
        }
        __syncthreads();
        xg_cur = xg_nxt;
    }

    if (row < 64) {
        float p = (float)sh_h[row] * Wlin[row] +
                  (float)sh_h[row + 64] * Wlin[row + 64];
#pragma unroll
        for (int off = 32; off > 0; off >>= 1) p += __shfl_down(p, off);
        if (row == 0) out[0] = sigmoid_f(p + blin[0]);
    }
}

extern "C" void kernel_launch(void* const* d_in, const int* in_sizes, int n_in,
                              void* d_out, int out_size, void* d_ws, size_t ws_size,
                              hipStream_t stream)
{
    const float* x    = (const float*)d_in[0];
    const float* Wih  = (const float*)d_in[1];
    const float* Whh  = (const float*)d_in[2];
    const float* bih  = (const float*)d_in[3];
    const float* bhh  = (const float*)d_in[4];
    const float* Wlin = (const float*)d_in[5];
    const float* blin = (const float*)d_in[6];
    float* out = (float*)d_out;

    const size_t need = (size_t)SEQ * G4 * sizeof(float); // 128 MB
    if (ws_size >= need) {
        float* xg = (float*)d_ws;
        xg_gemm<<<(SEQ * G4) / 256, 256, 0, stream>>>(x, Wih, bih, bhh, xg);
        lstm_scan<<<1, 512, 0, stream>>>(Whh, Wlin, blin, xg, out);
    } else {
        lstm_scan_fb<<<1, 512, 0, stream>>>(x, Wih, Whh, bih, bhh, Wlin,
                                            blin, out);
    }
}

// Round 10
// 29846.948 us; speedup vs baseline: 1.2538x; 1.2538x over previous
//
#include <hip/hip_runtime.h>

#define SEQ 65536
#define IN_DIM 64
#define H 128
#define G4 512
#define LOG2E 1.4426950408889634f

typedef _Float16 half_t;
typedef half_t half2_t __attribute__((ext_vector_type(2)));
typedef int    i4     __attribute__((ext_vector_type(4)));

__device__ __forceinline__ float fast_rcp(float x) { return __builtin_amdgcn_rcpf(x); }

__device__ __forceinline__ float exp2_fast(float x) {
#if __has_builtin(__builtin_amdgcn_exp2f)
    return __builtin_amdgcn_exp2f(x);
#else
    return exp2f(x);
#endif
}

// sigmoid of (u / log2e): u is PRE-SCALED by log2e -> rcp(1+exp2(-u)).
// Overflow-safe: exp2(+inf)->inf->rcp->0; exp2(-inf)->0->rcp(1)->1.
__device__ __forceinline__ float sig2(float u) {
    return fast_rcp(1.f + exp2_fast(-u));
}

// classic sigmoid (for the head + fallback kernel)
__device__ __forceinline__ float sigmoid_f(float x) {
    return sig2(x * LOG2E);
}

#if __has_builtin(__builtin_amdgcn_fdot2)
__device__ __forceinline__ float dot2i(int w, int h, float acc) {
    return __builtin_amdgcn_fdot2(__builtin_bit_cast(half2_t, w),
                                  __builtin_bit_cast(half2_t, h), acc, false);
}
#else
__device__ __forceinline__ float dot2i(int w, int h, float acc) {
    half2_t a = __builtin_bit_cast(half2_t, w);
    half2_t b = __builtin_bit_cast(half2_t, h);
    return acc + (float)a[0] * (float)b[0] + (float)a[1] * (float)b[1];
}
#endif

// two f32 -> one VGPR of packed 2xf16 (v_cvt_pkrtz_f16_f32)
__device__ __forceinline__ int pk(float a, float b) {
    return __builtin_bit_cast(int, __builtin_amdgcn_cvt_pkrtz(a, b));
}

// 8 fp32 -> int4 of packed half2s, scaled by s
__device__ __forceinline__ i4 cvt8i_s(const float* p, float s) {
    float4 a = *(const float4*)p;
    float4 b = *(const float4*)(p + 4);
    i4 r;
    r[0] = pk(a.x * s, a.y * s); r[1] = pk(a.z * s, a.w * s);
    r[2] = pk(b.x * s, b.y * s); r[3] = pk(b.z * s, b.w * s);
    return r;
}

// quad-lane exchange via DPP (VALU pipe). Control must be constant -> template.
template <int CTRL>
__device__ __forceinline__ float qperm(float x) {
    return __int_as_float(
        __builtin_amdgcn_mov_dpp(__float_as_int(x), CTRL, 0xF, 0xF, true));
}
#define qx1(x)  qperm<0xB1>(x) /* quad_perm [1,0,3,2] lane^1 */
#define qx2(x)  qperm<0x4E>(x) /* quad_perm [2,3,0,1] lane^2 */

// ---------------------------------------------------------------------------
// Phase A (tiled): xg[s][j*4+g] = (dot(x[s], W_ih[g*128+j]) + b) * LOG2E
// Block = 16 timesteps. x-tile staged in LDS (4 KB); thread t owns output
// positions {t, t+256} of each step -> W rows r0=(t&3)*128+(t>>2), r0+64,
// held in regs across the k-loop; 32 f32 accumulators (16 s x 2 rows).
// Fixes the R1-R9 gemm: 17.5 GB fetch (512 B/output, zero reuse) -> ~16 MB.
// ---------------------------------------------------------------------------
__global__ __launch_bounds__(256) void xg_gemm_t(
    const float* __restrict__ x, const float* __restrict__ Wih,
    const float* __restrict__ bih, const float* __restrict__ bhh,
    float* __restrict__ xg)
{
    __shared__ __align__(16) float sx[16 * IN_DIM]; // 4 KB
    const int t  = threadIdx.x;
    const int s0 = blockIdx.x * 16;

    // cooperative x-tile load: 1024 floats / 256 thr = 1 float4 each
    *(float4*)&sx[t * 4] = *(const float4*)(x + (size_t)s0 * IN_DIM + t * 4);
    __syncthreads();

    const int r0 = (t & 3) * H + (t >> 2);
    const int r1 = r0 + 64;
    const float* w0p = Wih + (size_t)r0 * IN_DIM;
    const float* w1p = Wih + (size_t)r1 * IN_DIM;

    float acc0[16], acc1[16];
#pragma unroll
    for (int s = 0; s < 16; ++s) { acc0[s] = 0.f; acc1[s] = 0.f; }

#pragma unroll
    for (int k = 0; k < IN_DIM; k += 4) {
        float4 w0 = *(const float4*)(w0p + k);
        float4 w1 = *(const float4*)(w1p + k);
#pragma unroll
        for (int s = 0; s < 16; ++s) {
            float4 xv = *(const float4*)&sx[s * IN_DIM + k];
            acc0[s] += w0.x * xv.x + w0.y * xv.y + w0.z * xv.z + w0.w * xv.w;
            acc1[s] += w1.x * xv.x + w1.y * xv.y + w1.z * xv.z + w1.w * xv.w;
        }
    }

    const float b0 = bih[r0] + bhh[r0];
    const float b1 = bih[r1] + bhh[r1];
#pragma unroll
    for (int s = 0; s < 16; ++s) {
        xg[(size_t)(s0 + s) * G4 + t]       = (acc0[s] + b0) * LOG2E;
        xg[(size_t)(s0 + s) * G4 + t + 256] = (acc1[s] + b1) * LOG2E;
    }
}

// ---------------------------------------------------------------------------
// Phase B: persistent 256-thread (4-wave, 1/SIMD) scan — R5 geometry.
// Quad owns cells {j0, j0+1}; lane ql owns k-slice [ql*32, ql*32+32) of all
// 8 gate rows (128 f16 = 64 packed VGPRs... plus working set; waves_per_eu(1,1)
// gives the 256-reg budget, PIN blocks load-sinking).
// Step: 4x ds_read_b128 (h) -> i/f dots -> i/f QRED -> sigma_i/f (overlaps
// g/o dots below, staggered) -> g/o dots -> g/o QRED -> finalize WITHOUT
// routing: the 2-hop butterfly already gives EVERY lane all 8 full sums, so
// lane ql finalizes cell j0+(ql&1) completely (c replicated x2; lanes ql<2
// write h). sigma = rcp(1+exp2(-u)) with log2e pre-folded into W_hh and xg.
// One raw barrier with lgkmcnt-only drain; depth-2 xg float4 ring rides
// across barriers (vmcnt never force-drained).
// ---------------------------------------------------------------------------
__attribute__((amdgpu_waves_per_eu(1, 1)))
__global__ __launch_bounds__(256) void lstm_scan(
    const float* __restrict__ Whh, const float* __restrict__ Wlin,
    const float* __restrict__ blin, const float* __restrict__ xg,
    float* __restrict__ out)
{
    __shared__ __align__(16) half_t shbuf[2][H]; // 512 B double-buffered h
    const int tid = threadIdx.x;
    const int ql  = tid & 3;
    const int j0  = (tid >> 2) * 2;
    const int c0  = ql * 32;
    const int jF  = j0 + (ql & 1);   // the cell this lane finalizes

    // ---- weights: 8 rows x 32 cols, packed f16, pre-scaled by LOG2E ----
#define LOADW(P, ROW)                                                     \
    i4 P##0 = cvt8i_s(Whh + (size_t)(ROW) * H + c0 + 0,  LOG2E),          \
       P##1 = cvt8i_s(Whh + (size_t)(ROW) * H + c0 + 8,  LOG2E),          \
       P##2 = cvt8i_s(Whh + (size_t)(ROW) * H + c0 + 16, LOG2E),          \
       P##3 = cvt8i_s(Whh + (size_t)(ROW) * H + c0 + 24, LOG2E);
    LOADW(wi0, j0)           LOADW(wi1, j0 + 1)
    LOADW(wf0, 128 + j0)     LOADW(wf1, 129 + j0)
    LOADW(wg0, 256 + j0)     LOADW(wg1, 257 + j0)
    LOADW(wo0, 384 + j0)     LOADW(wo1, 385 + j0)
#undef LOADW
#define PIN(A, B, C, D) asm volatile("" : "+v"(A), "+v"(B), "+v"(C), "+v"(D))
    PIN(wi00, wi01, wi02, wi03); PIN(wi10, wi11, wi12, wi13);
    PIN(wf00, wf01, wf02, wf03); PIN(wf10, wf11, wf12, wf13);
    PIN(wg00, wg01, wg02, wg03); PIN(wg10, wg11, wg12, wg13);
    PIN(wo00, wo01, wo02, wo03); PIN(wo10, wo11, wo12, wo13);
#undef PIN

    const float* xgq = xg + (size_t)jF * 4; // [s][j][gate] float4 for my cell
    float c = 0.f;
    const float K2 = 2.f * LOG2E;

    // xg ring: depth-2 prefetch
    float4 xg_c = *(const float4*)(xgq + (size_t)0 * G4);
    float4 xg_n = *(const float4*)(xgq + (size_t)1 * G4);

    if (tid < H) shbuf[0][tid] = (half_t)0.f;
    __syncthreads();

#define DOT8(ACC, WV, HV)                                                 \
    ACC = dot2i(WV[0], HV[0], ACC);                                       \
    ACC = dot2i(WV[1], HV[1], ACC);                                       \
    ACC = dot2i(WV[2], HV[2], ACC);                                       \
    ACC = dot2i(WV[3], HV[3], ACC);
#define DROW(ACC, P)                                                      \
    DOT8(ACC, P##0, h0) DOT8(ACC, P##1, h1)                               \
    DOT8(ACC, P##2, h2) DOT8(ACC, P##3, h3)
#define QRED(X) X += qx1(X); X += qx2(X);

#define STEP(RB, WB, T)                                                   \
    {                                                                     \
        const i4* hp = (const i4*)&shbuf[RB][c0];                         \
        i4 h0 = hp[0], h1 = hp[1], h2 = hp[2], h3 = hp[3];                \
        int tp = (T) + 2; if (tp > SEQ - 1) tp = SEQ - 1;                 \
        float4 xg_p = *(const float4*)(xgq + (size_t)tp * G4);            \
        float ai0 = 0.f, ai1 = 0.f, af0 = 0.f, af1 = 0.f;                 \
        float ag0 = 0.f, ag1 = 0.f, ao0 = 0.f, ao1 = 0.f;                 \
        DROW(ai0, wi0) DROW(ai1, wi1)                                     \
        DROW(af0, wf0) DROW(af1, wf1)                                     \
        QRED(ai0) QRED(ai1) QRED(af0) QRED(af1)                           \
        float si = (ql & 1) ? ai1 : ai0;                                  \
        float sf = (ql & 1) ? af1 : af0;                                  \
        float gi = sig2(si + xg_c.x);   /* overlaps g/o dots below */     \
        float gf = sig2(sf + xg_c.y);                                     \
        DROW(ag0, wg0) DROW(ag1, wg1)                                     \
        DROW(ao0, wo0) DROW(ao1, wo1)                                     \
        QRED(ag0) QRED(ag1) QRED(ao0) QRED(ao1)                           \
        float sg = (ql & 1) ? ag1 : ag0;                                  \
        float so = (ql & 1) ? ao1 : ao0;                                  \
        float ug = sg + xg_c.z;                                           \
        float s2g = sig2(ug + ug);                                        \
        float gg = s2g + s2g - 1.f;      /* tanh = 2*sig(2x)-1 */         \
        float go = sig2(so + xg_c.w);                                     \
        c = gf * c + gi * gg;                                             \
        float sc = sig2(c * K2);                                          \
        float th = sc + sc - 1.f;                                         \
        float hh = go * th;                                               \
        if (ql < 2) shbuf[WB][jF] = (half_t)hh;                           \
        asm volatile("s_waitcnt lgkmcnt(0)" ::: "memory");                \
        __builtin_amdgcn_s_barrier();                                     \
        __builtin_amdgcn_sched_barrier(0);                                \
        xg_c = xg_n; xg_n = xg_p;                                         \
    }

    for (int t = 0; t < SEQ; t += 2) {
        STEP(0, 1, t)
        STEP(1, 0, t + 1)
    }
#undef STEP
#undef QRED
#undef DROW
#undef DOT8

    // h(SEQ) in shbuf[0]; one wave reduces the linear head (unscaled math).
    if (tid < 64) {
        float p = (float)shbuf[0][tid] * Wlin[tid] +
                  (float)shbuf[0][tid + 64] * Wlin[tid + 64];
#pragma unroll
        for (int off = 32; off > 0; off >>= 1) p += __shfl_down(p, off);
        if (tid == 0) out[0] = sigmoid_f(p + blin[0]);
    }
}

// ---------------------------------------------------------------------------
// Fallback (ws too small): self-contained, known-correct (R2 structure).
// ---------------------------------------------------------------------------
__global__ __launch_bounds__(512, 2) void lstm_scan_fb(
    const float* __restrict__ x, const float* __restrict__ Wih,
    const float* __restrict__ Whh, const float* __restrict__ bih,
    const float* __restrict__ bhh, const float* __restrict__ Wlin,
    const float* __restrict__ blin, float* __restrict__ out)
{
    __shared__ __align__(16) half_t sh_h[H];
    __shared__ __align__(16) float  sh_g[G4];
    const int row = threadIdx.x;
    const float* wrow = Whh + (long long)row * H;

    i4 w0 = cvt8i_s(wrow + 0, 1.f),   w1 = cvt8i_s(wrow + 8, 1.f);
    i4 w2 = cvt8i_s(wrow + 16, 1.f),  w3 = cvt8i_s(wrow + 24, 1.f);
    i4 w4 = cvt8i_s(wrow + 32, 1.f),  w5 = cvt8i_s(wrow + 40, 1.f);
    i4 w6 = cvt8i_s(wrow + 48, 1.f),  w7 = cvt8i_s(wrow + 56, 1.f);
    i4 w8 = cvt8i_s(wrow + 64, 1.f),  w9 = cvt8i_s(wrow + 72, 1.f);
    i4 w10 = cvt8i_s(wrow + 80, 1.f), w11 = cvt8i_s(wrow + 88, 1.f);
    i4 w12 = cvt8i_s(wrow + 96, 1.f), w13 = cvt8i_s(wrow + 104, 1.f);
    i4 w14 = cvt8i_s(wrow + 112, 1.f), w15 = cvt8i_s(wrow + 120, 1.f);

    const float bsum = bih[row] + bhh[row];
    float c = 0.f;
    if (row < H) sh_h[row] = (half_t)0.f;

    float xg_cur;
    {
        float a = bsum;
        const float* wir = Wih + (long long)row * IN_DIM;
#pragma unroll
        for (int k = 0; k < IN_DIM; k += 4) {
            float4 iv = *(const float4*)(x + k);
            float4 wv = *(const float4*)(wir + k);
            a += wv.x * iv.x + wv.y * iv.y + wv.z * iv.z + wv.w * iv.w;
        }
        xg_cur = a;
    }
    const bool is_g = (row >= 2 * H) && (row < 3 * H);
    __syncthreads();

    const i4* hch = (const i4*)sh_h;

    for (int t = 0; t < SEQ; ++t) {
        float xg_nxt = 0.f;
        if (t + 1 < SEQ) {
            const float* xr = x + (size_t)(t + 1) * IN_DIM;
            const float* wir = Wih + (long long)row * IN_DIM;
            float a = bsum;
#pragma unroll
            for (int k = 0; k < IN_DIM; k += 4) {
                float4 iv = *(const float4*)(xr + k);
                float4 wv = *(const float4*)(wir + k);
                a += wv.x * iv.x + wv.y * iv.y + wv.z * iv.z + wv.w * iv.w;
            }
            xg_nxt = a;
        }
        float a0 = 0.f, a1 = 0.f, a2 = 0.f, a3 = 0.f;
#define DOTC(WV, CI)                                                     \
        {   i4 hv = hch[CI];                                             \
            a0 = dot2i(WV[0], hv[0], a0);                                \
            a1 = dot2i(WV[1], hv[1], a1);                                \
            a2 = dot2i(WV[2], hv[2], a2);                                \
            a3 = dot2i(WV[3], hv[3], a3); }
        DOTC(w0, 0)  DOTC(w1, 1)  DOTC(w2, 2)   DOTC(w3, 3)
        DOTC(w4, 4)  DOTC(w5, 5)  DOTC(w6, 6)   DOTC(w7, 7)
        DOTC(w8, 8)  DOTC(w9, 9)  DOTC(w10, 10) DOTC(w11, 11)
        DOTC(w12, 12) DOTC(w13, 13) DOTC(w14, 14) DOTC(w15, 15)
#undef DOTC
        float pre = xg_cur + ((a0 + a1) + (a2 + a3));
        float gv;
        if (is_g) {
            float s = sigmoid_f(pre + pre);
            gv = s + s - 1.f;
        } else {
            gv = sigmoid_f(pre);
        }
        sh_g[row] = gv;
        __syncthreads();
        if (row >= 3 * H) {
            int jj = row - 3 * H;
            float ig = sh_g[jj];
            float fg = sh_g[H + jj];
            float gg = sh_g[2 * H + jj];
            c = fg * c + ig * gg;
            float s = sigmoid_f(c + c);
            sh_h[jj] = (half_t)(gv * (s + s - 1.f));
        }
        __syncthreads();
        xg_cur = xg_nxt;
    }

    if (row < 64) {
        float p = (float)sh_h[row] * Wlin[row] +
                  (float)sh_h[row + 64] * Wlin[row + 64];
#pragma unroll
        for (int off = 32; off > 0; off >>= 1) p += __shfl_down(p, off);
        if (row == 0) out[0] = sigmoid_f(p + blin[0]);
    }
}

extern "C" void kernel_launch(void* const* d_in, const int* in_sizes, int n_in,
                              void* d_out, int out_size, void* d_ws, size_t ws_size,
                              hipStream_t stream)
{
    const float* x    = (const float*)d_in[0];
    const float* Wih  = (const float*)d_in[1];
    const float* Whh  = (const float*)d_in[2];
    const float* bih  = (const float*)d_in[3];
    const float* bhh  = (const float*)d_in[4];
    const float* Wlin = (const float*)d_in[5];
    const float* blin = (const float*)d_in[6];
    float* out = (float*)d_out;

    const size_t need = (size_t)SEQ * G4 * sizeof(float); // 128 MB
    if (ws_size >= need) {
        float* xg = (float*)d_ws;
        xg_gemm_t<<<SEQ / 16, 256, 0, stream>>>(x, Wih, bih, bhh, xg);
        lstm_scan<<<1, 256, 0, stream>>>(Whh, Wlin, blin, xg, out);
    } else {
        lstm_scan_fb<<<1, 512, 0, stream>>>(x, Wih, Whh, bih, bhh, Wlin,
                                            blin, out);
    }
}

// Round 11
// 29084.637 us; speedup vs baseline: 1.2867x; 1.0262x over previous
//
#include <hip/hip_runtime.h>

#define SEQ 65536
#define IN_DIM 64
#define H 128
#define G4 512
#define LOG2E 1.4426950408889634f

typedef _Float16 half_t;
typedef half_t half2_t __attribute__((ext_vector_type(2)));
typedef int    i4     __attribute__((ext_vector_type(4)));

__device__ __forceinline__ float fast_rcp(float x) { return __builtin_amdgcn_rcpf(x); }

__device__ __forceinline__ float exp2_fast(float x) {
#if __has_builtin(__builtin_amdgcn_exp2f)
    return __builtin_amdgcn_exp2f(x);
#else
    return exp2f(x);
#endif
}

// sigmoid of (u / log2e): u PRE-SCALED by log2e -> rcp(1+exp2(-u)).
// Overflow-safe: exp2(+inf)->inf->rcp->0; exp2(-inf)->0->rcp(1)->1.
__device__ __forceinline__ float sig2(float u) {
    return fast_rcp(1.f + exp2_fast(-u));
}

__device__ __forceinline__ float sigmoid_f(float x) {
    return sig2(x * LOG2E);
}

#if __has_builtin(__builtin_amdgcn_fdot2)
__device__ __forceinline__ float dot2i(int w, int h, float acc) {
    return __builtin_amdgcn_fdot2(__builtin_bit_cast(half2_t, w),
                                  __builtin_bit_cast(half2_t, h), acc, false);
}
#else
__device__ __forceinline__ float dot2i(int w, int h, float acc) {
    half2_t a = __builtin_bit_cast(half2_t, w);
    half2_t b = __builtin_bit_cast(half2_t, h);
    return acc + (float)a[0] * (float)b[0] + (float)a[1] * (float)b[1];
}
#endif

// two f32 -> one VGPR of packed 2xf16 (v_cvt_pkrtz_f16_f32)
__device__ __forceinline__ int pk(float a, float b) {
    return __builtin_bit_cast(int, __builtin_amdgcn_cvt_pkrtz(a, b));
}

// 8 fp32 -> int4 of packed half2s, scaled by s
__device__ __forceinline__ i4 cvt8i_s(const float* p, float s) {
    float4 a = *(const float4*)p;
    float4 b = *(const float4*)(p + 4);
    i4 r;
    r[0] = pk(a.x * s, a.y * s); r[1] = pk(a.z * s, a.w * s);
    r[2] = pk(b.x * s, b.y * s); r[3] = pk(b.z * s, b.w * s);
    return r;
}

// quad-lane exchange via DPP (VALU pipe). Control must be constant -> template.
template <int CTRL>
__device__ __forceinline__ float qperm(float x) {
    return __int_as_float(
        __builtin_amdgcn_mov_dpp(__float_as_int(x), CTRL, 0xF, 0xF, true));
}
#define qx1(x)  qperm<0xB1>(x) /* quad_perm [1,0,3,2] lane^1 */
#define qx2(x)  qperm<0x4E>(x) /* quad_perm [2,3,0,1] lane^2 */

// ---------------------------------------------------------------------------
// Phase A (tiled): xg[s][j*4+g] = (dot(x[s], W_ih[g*128+j]) + b) * LOG2E
// Block = 16 timesteps; x-tile in LDS; W rows in regs; ~16 MB total fetch.
// ---------------------------------------------------------------------------
__global__ __launch_bounds__(256) void xg_gemm_t(
    const float* __restrict__ x, const float* __restrict__ Wih,
    const float* __restrict__ bih, const float* __restrict__ bhh,
    float* __restrict__ xg)
{
    __shared__ __align__(16) float sx[16 * IN_DIM]; // 4 KB
    const int t  = threadIdx.x;
    const int s0 = blockIdx.x * 16;

    *(float4*)&sx[t * 4] = *(const float4*)(x + (size_t)s0 * IN_DIM + t * 4);
    __syncthreads();

    const int r0 = (t & 3) * H + (t >> 2);
    const int r1 = r0 + 64;
    const float* w0p = Wih + (size_t)r0 * IN_DIM;
    const float* w1p = Wih + (size_t)r1 * IN_DIM;

    float acc0[16], acc1[16];
#pragma unroll
    for (int s = 0; s < 16; ++s) { acc0[s] = 0.f; acc1[s] = 0.f; }

#pragma unroll
    for (int k = 0; k < IN_DIM; k += 4) {
        float4 w0 = *(const float4*)(w0p + k);
        float4 w1 = *(const float4*)(w1p + k);
#pragma unroll
        for (int s = 0; s < 16; ++s) {
            float4 xv = *(const float4*)&sx[s * IN_DIM + k];
            acc0[s] += w0.x * xv.x + w0.y * xv.y + w0.z * xv.z + w0.w * xv.w;
            acc1[s] += w1.x * xv.x + w1.y * xv.y + w1.z * xv.z + w1.w * xv.w;
        }
    }

    const float b0 = bih[r0] + bhh[r0];
    const float b1 = bih[r1] + bhh[r1];
#pragma unroll
    for (int s = 0; s < 16; ++s) {
        xg[(size_t)(s0 + s) * G4 + t]       = (acc0[s] + b0) * LOG2E;
        xg[(size_t)(s0 + s) * G4 + t + 256] = (acc1[s] + b1) * LOG2E;
    }
}

// ---------------------------------------------------------------------------
// Phase B: persistent 256-thread (4-wave, 1/SIMD) scan.
// R10 geometry; this round shortens the SERIAL TAIL (the ~700 cyc/step of
// exposed latency R10's calibration isolated):
//  - gate order g->i->f->o: sigma_g/i/f hide under the next gate's dots;
//    only sigma_o is in the tail, parallel with the c-fma->tanh chain.
//  - fused select+butterfly GRED: 6 instrs / 4-deep (was 9 / 8-deep).
//  - packed h-write: 1 ds_write_b32 per quad (lane 0) via DPP+cvt_pkrtz.
// ---------------------------------------------------------------------------
__attribute__((amdgpu_waves_per_eu(1, 1)))
__global__ __launch_bounds__(256) void lstm_scan(
    const float* __restrict__ Whh, const float* __restrict__ Wlin,
    const float* __restrict__ blin, const float* __restrict__ xg,
    float* __restrict__ out)
{
    __shared__ __align__(16) half_t shbuf[2][H]; // 512 B double-buffered h
    const int tid = threadIdx.x;
    const int ql  = tid & 3;
    const int j0  = (tid >> 2) * 2;
    const int c0  = ql * 32;
    const int jF  = j0 + (ql & 1);   // the cell this lane finalizes

    // ---- weights: 8 rows x 32 cols, packed f16, pre-scaled by LOG2E ----
#define LOADW(P, ROW)                                                     \
    i4 P##0 = cvt8i_s(Whh + (size_t)(ROW) * H + c0 + 0,  LOG2E),          \
       P##1 = cvt8i_s(Whh + (size_t)(ROW) * H + c0 + 8,  LOG2E),          \
       P##2 = cvt8i_s(Whh + (size_t)(ROW) * H + c0 + 16, LOG2E),          \
       P##3 = cvt8i_s(Whh + (size_t)(ROW) * H + c0 + 24, LOG2E);
    LOADW(wi0, j0)           LOADW(wi1, j0 + 1)
    LOADW(wf0, 128 + j0)     LOADW(wf1, 129 + j0)
    LOADW(wg0, 256 + j0)     LOADW(wg1, 257 + j0)
    LOADW(wo0, 384 + j0)     LOADW(wo1, 385 + j0)
#undef LOADW
#define PIN(A, B, C, D) asm volatile("" : "+v"(A), "+v"(B), "+v"(C), "+v"(D))
    PIN(wi00, wi01, wi02, wi03); PIN(wi10, wi11, wi12, wi13);
    PIN(wf00, wf01, wf02, wf03); PIN(wf10, wf11, wf12, wf13);
    PIN(wg00, wg01, wg02, wg03); PIN(wg10, wg11, wg12, wg13);
    PIN(wo00, wo01, wo02, wo03); PIN(wo10, wo11, wo12, wo13);
#undef PIN

    const float* xgq = xg + (size_t)jF * 4; // [s][j][gate] float4 for my cell
    float c = 0.f;
    const float K2 = 2.f * LOG2E;

    // xg ring: depth-2 prefetch
    float4 xg_c = *(const float4*)(xgq + (size_t)0 * G4);
    float4 xg_n = *(const float4*)(xgq + (size_t)1 * G4);

    if (tid < H) shbuf[0][tid] = (half_t)0.f;
    __syncthreads();

#define DOT8(ACC, WV, HV)                                                 \
    ACC = dot2i(WV[0], HV[0], ACC);                                       \
    ACC = dot2i(WV[1], HV[1], ACC);                                       \
    ACC = dot2i(WV[2], HV[2], ACC);                                       \
    ACC = dot2i(WV[3], HV[3], ACC);
#define DROW(ACC, P)                                                      \
    DOT8(ACC, P##0, h0) DOT8(ACC, P##1, h1)                               \
    DOT8(ACC, P##2, h2) DOT8(ACC, P##3, h3)
// fused select + 2-hop butterfly: S = full row-sum for cell jF's row of
// this gate. Partner lane's "other" slot holds my row's missing slice.
#define GRED(S, A0, A1)                                                   \
    float S;                                                              \
    {   S        = (ql & 1) ? (A1) : (A0);                                \
        float b_ = (ql & 1) ? (A0) : (A1);                                \
        S += qx1(b_);                                                     \
        S += qx2(S); }

#define STEP(RB, WB, T)                                                   \
    {                                                                     \
        const i4* hp = (const i4*)&shbuf[RB][c0];                         \
        i4 h0 = hp[0], h1 = hp[1], h2 = hp[2], h3 = hp[3];                \
        int tp = (T) + 2; if (tp > SEQ - 1) tp = SEQ - 1;                 \
        float4 xg_p = *(const float4*)(xgq + (size_t)tp * G4);            \
        float ag0 = 0.f, ag1 = 0.f, ai0 = 0.f, ai1 = 0.f;                 \
        float af0 = 0.f, af1 = 0.f, ao0 = 0.f, ao1 = 0.f;                 \
        /* g first: its sigma is the longest pole (feeds c) */            \
        DROW(ag0, wg0) DROW(ag1, wg1)                                     \
        GRED(sg, ag0, ag1)                                                \
        float ug  = sg + xg_c.z;                                          \
        float s2g = sig2(ug + ug);                                        \
        float gg  = s2g + s2g - 1.f;   /* tanh = 2*sig(2x)-1 */           \
        DROW(ai0, wi0) DROW(ai1, wi1)                                     \
        GRED(si, ai0, ai1)                                                \
        float gi = sig2(si + xg_c.x);                                     \
        DROW(af0, wf0) DROW(af1, wf1)                                     \
        GRED(sf, af0, af1)                                                \
        float gf = sig2(sf + xg_c.y);                                     \
        DROW(ao0, wo0) DROW(ao1, wo1)                                     \
        GRED(so, ao0, ao1)                                                \
        float go = sig2(so + xg_c.w); /* parallel with c-chain below */   \
        c = gf * c + gi * gg;                                             \
        float sc = sig2(c * K2);                                          \
        float th = sc + sc - 1.f;                                         \
        float hh = go * th;                                               \
        float ho = qx1(hh);            /* partner cell's h */             \
        if (ql == 0)                                                      \
            ((int*)&shbuf[WB][0])[j0 >> 1] = pk(hh, ho);                  \
        asm volatile("s_waitcnt lgkmcnt(0)" ::: "memory");                \
        __builtin_amdgcn_s_barrier();                                     \
        __builtin_amdgcn_sched_barrier(0);                                \
        xg_c = xg_n; xg_n = xg_p;                                         \
    }

    for (int t = 0; t < SEQ; t += 2) {
        STEP(0, 1, t)
        STEP(1, 0, t + 1)
    }
#undef STEP
#undef GRED
#undef DROW
#undef DOT8

    // h(SEQ) in shbuf[0]; one wave reduces the linear head.
    if (tid < 64) {
        float p = (float)shbuf[0][tid] * Wlin[tid] +
                  (float)shbuf[0][tid + 64] * Wlin[tid + 64];
#pragma unroll
        for (int off = 32; off > 0; off >>= 1) p += __shfl_down(p, off);
        if (tid == 0) out[0] = sigmoid_f(p + blin[0]);
    }
}

// ---------------------------------------------------------------------------
// Fallback (ws too small): self-contained, known-correct (R2 structure).
// ---------------------------------------------------------------------------
__global__ __launch_bounds__(512, 2) void lstm_scan_fb(
    const float* __restrict__ x, const float* __restrict__ Wih,
    const float* __restrict__ Whh, const float* __restrict__ bih,
    const float* __restrict__ bhh, const float* __restrict__ Wlin,
    const float* __restrict__ blin, float* __restrict__ out)
{
    __shared__ __align__(16) half_t sh_h[H];
    __shared__ __align__(16) float  sh_g[G4];
    const int row = threadIdx.x;
    const float* wrow = Whh + (long long)row * H;

    i4 w0 = cvt8i_s(wrow + 0, 1.f),   w1 = cvt8i_s(wrow + 8, 1.f);
    i4 w2 = cvt8i_s(wrow + 16, 1.f),  w3 = cvt8i_s(wrow + 24, 1.f);
    i4 w4 = cvt8i_s(wrow + 32, 1.f),  w5 = cvt8i_s(wrow + 40, 1.f);
    i4 w6 = cvt8i_s(wrow + 48, 1.f),  w7 = cvt8i_s(wrow + 56, 1.f);
    i4 w8 = cvt8i_s(wrow + 64, 1.f),  w9 = cvt8i_s(wrow + 72, 1.f);
    i4 w10 = cvt8i_s(wrow + 80, 1.f), w11 = cvt8i_s(wrow + 88, 1.f);
    i4 w12 = cvt8i_s(wrow + 96, 1.f), w13 = cvt8i_s(wrow + 104, 1.f);
    i4 w14 = cvt8i_s(wrow + 112, 1.f), w15 = cvt8i_s(wrow + 120, 1.f);

    const float bsum = bih[row] + bhh[row];
    float c = 0.f;
    if (row < H) sh_h[row] = (half_t)0.f;

    float xg_cur;
    {
        float a = bsum;
        const float* wir = Wih + (long long)row * IN_DIM;
#pragma unroll
        for (int k = 0; k < IN_DIM; k += 4) {
            float4 iv = *(const float4*)(x + k);
            float4 wv = *(const float4*)(wir + k);
            a += wv.x * iv.x + wv.y * iv.y + wv.z * iv.z + wv.w * iv.w;
        }
        xg_cur = a;
    }
    const bool is_g = (row >= 2 * H) && (row < 3 * H);
    __syncthreads();

    const i4* hch = (const i4*)sh_h;

    for (int t = 0; t < SEQ; ++t) {
        float xg_nxt = 0.f;
        if (t + 1 < SEQ) {
            const float* xr = x + (size_t)(t + 1) * IN_DIM;
            const float* wir = Wih + (long long)row * IN_DIM;
            float a = bsum;
#pragma unroll
            for (int k = 0; k < IN_DIM; k += 4) {
                float4 iv = *(const float4*)(xr + k);
                float4 wv = *(const float4*)(wir + k);
                a += wv.x * iv.x + wv.y * iv.y + wv.z * iv.z + wv.w * iv.w;
            }
            xg_nxt = a;
        }
        float a0 = 0.f, a1 = 0.f, a2 = 0.f, a3 = 0.f;
#define DOTC(WV, CI)                                                     \
        {   i4 hv = hch[CI];                                             \
            a0 = dot2i(WV[0], hv[0], a0);                                \
            a1 = dot2i(WV[1], hv[1], a1);                                \
            a2 = dot2i(WV[2], hv[2], a2);                                \
            a3 = dot2i(WV[3], hv[3], a3); }
        DOTC(w0, 0)  DOTC(w1, 1)  DOTC(w2, 2)   DOTC(w3, 3)
        DOTC(w4, 4)  DOTC(w5, 5)  DOTC(w6, 6)   DOTC(w7, 7)
        DOTC(w8, 8)  DOTC(w9, 9)  DOTC(w10, 10) DOTC(w11, 11)
        DOTC(w12, 12) DOTC(w13, 13) DOTC(w14, 14) DOTC(w15, 15)
#undef DOTC
        float pre = xg_cur + ((a0 + a1) + (a2 + a3));
        float gv;
        if (is_g) {
            float s = sigmoid_f(pre + pre);
            gv = s + s - 1.f;
        } else {
            gv = sigmoid_f(pre);
        }
        sh_g[row] = gv;
        __syncthreads();
        if (row >= 3 * H) {
            int jj = row - 3 * H;
            float ig = sh_g[jj];
            float fg = sh_g[H + jj];
            float gg = sh_g[2 * H + jj];
            c = fg * c + ig * gg;
            float s = sigmoid_f(c + c);
            sh_h[jj] = (half_t)(gv * (s + s - 1.f));
        }
        __syncthreads();
        xg_cur = xg_nxt;
    }

    if (row < 64) {
        float p = (float)sh_h[row] * Wlin[row] +
                  (float)sh_h[row + 64] * Wlin[row + 64];
#pragma unroll
        for (int off = 32; off > 0; off >>= 1) p += __shfl_down(p, off);
        if (row == 0) out[0] = sigmoid_f(p + blin[0]);
    }
}

extern "C" void kernel_launch(void* const* d_in, const int* in_sizes, int n_in,
                              void* d_out, int out_size, void* d_ws, size_t ws_size,
                              hipStream_t stream)
{
    const float* x    = (const float*)d_in[0];
    const float* Wih  = (const float*)d_in[1];
    const float* Whh  = (const float*)d_in[2];
    const float* bih  = (const float*)d_in[3];
    const float* bhh  = (const float*)d_in[4];
    const float* Wlin = (const float*)d_in[5];
    const float* blin = (const float*)d_in[6];
    float* out = (float*)d_out;

    const size_t need = (size_t)SEQ * G4 * sizeof(float); // 128 MB
    if (ws_size >= need) {
        float* xg = (float*)d_ws;
        xg_gemm_t<<<SEQ / 16, 256, 0, stream>>>(x, Wih, bih, bhh, xg);
        lstm_scan<<<1, 256, 0, stream>>>(Whh, Wlin, blin, xg, out);
    } else {
        lstm_scan_fb<<<1, 512, 0, stream>>>(x, Wih, Whh, bih, bhh, Wlin,
                                            blin, out);
    }
}